// Round 3
// baseline (304.715 us; speedup 1.0000x reference)
//
#include <hip/hip_runtime.h>
#include <hip/hip_cooperative_groups.h>
#include <math.h>

namespace cg = cooperative_groups;

#define MASK_THR 0.53f
#define BT 32

// Stage 1: priority scatter, 32-bit packed atomics.
// p in [0.53, 1.0) => float exponent fixed at 126, so the 23 mantissa bits
// order identically to p. The final output depends only on the winner's
// instance n (label n+1), not its pixel, so the tie-break (min flat index ==
// min n among prob-ties) needs only n: pack (mant << 9) | (NB1 - n).
// atomicMax => max prob, tie -> min n. Exact.
__global__ void k_scatter(const float* __restrict__ prob,
                          const int* __restrict__ coords,  // [2, NE] flat
                          unsigned* __restrict__ packed,
                          int NE, int HW, int NB1,
                          const int* __restrict__ d_size1) {
    int i4 = blockIdx.x * blockDim.x + threadIdx.x;
    int base = i4 * 4;
    if (base >= NE) return;
    int size1 = *d_size1;
    float4 p = ((const float4*)prob)[i4];
    int4 x = ((const int4*)coords)[i4];
    int4 y = ((const int4*)(coords + NE))[i4];
    float pv[4] = {p.x, p.y, p.z, p.w};
    int   xv[4] = {x.x, x.y, x.z, x.w};
    int   yv[4] = {y.x, y.y, y.z, y.w};
#pragma unroll
    for (int e = 0; e < 4; ++e) {
        if (pv[e] >= MASK_THR) {
            unsigned n = (unsigned)(base + e) / (unsigned)HW;
            unsigned v = ((__float_as_uint(pv[e]) & 0x7FFFFFu) << 9) |
                         (unsigned)(NB1 - (int)n);
            atomicMax(&packed[xv[e] * size1 + yv[e]], v);
        }
    }
}

// One 32x32 output tile per block, 2x2 register blocking, 256 threads.
// addIA: treat both inputs as (X + I) while loading (used for M^2 = (A+I)^2).
__device__ __forceinline__ void mm_tile(const float* __restrict__ A,
                                        const float* __restrict__ B,
                                        float* __restrict__ C, int N, bool addI,
                                        float (&As)[BT][BT + 1],
                                        float (&Bs)[BT][BT + 1]) {
    int tid = threadIdx.x;
    int NT = N / BT;
    int bx = blockIdx.x % NT, by = blockIdx.x / NT;
    int rowBase = by * BT, colBase = bx * BT;
    int tx = tid & 15, ty = tid >> 4;
    int lr = tid >> 3;
    int lc = (tid & 7) * 4;
    float a00 = 0, a01 = 0, a10 = 0, a11 = 0;
    for (int t = 0; t < N; t += BT) {
        float4 av = *(const float4*)&A[(size_t)(rowBase + lr) * N + t + lc];
        float4 bv = *(const float4*)&B[(size_t)(t + lr) * N + colBase + lc];
        if (addI) {
            int r = rowBase + lr, c = t + lc;
            if (r == c + 0) av.x += 1.0f;
            if (r == c + 1) av.y += 1.0f;
            if (r == c + 2) av.z += 1.0f;
            if (r == c + 3) av.w += 1.0f;
            int r2 = t + lr, c2 = colBase + lc;
            if (r2 == c2 + 0) bv.x += 1.0f;
            if (r2 == c2 + 1) bv.y += 1.0f;
            if (r2 == c2 + 2) bv.z += 1.0f;
            if (r2 == c2 + 3) bv.w += 1.0f;
        }
        As[lr][lc + 0] = av.x; As[lr][lc + 1] = av.y;
        As[lr][lc + 2] = av.z; As[lr][lc + 3] = av.w;
        Bs[lr][lc + 0] = bv.x; Bs[lr][lc + 1] = bv.y;
        Bs[lr][lc + 2] = bv.z; Bs[lr][lc + 3] = bv.w;
        __syncthreads();
#pragma unroll
        for (int k = 0; k < BT; ++k) {
            float a0 = As[ty * 2][k], a1 = As[ty * 2 + 1][k];
            float b0 = Bs[k][tx * 2], b1 = Bs[k][tx * 2 + 1];
            a00 += a0 * b0; a01 += a0 * b1;
            a10 += a1 * b0; a11 += a1 * b1;
        }
        __syncthreads();
    }
    int r0 = rowBase + ty * 2, c0 = colBase + tx * 2;
    C[(size_t)r0 * N + c0] = a00;
    C[(size_t)r0 * N + c0 + 1] = a01;
    C[(size_t)(r0 + 1) * N + c0] = a10;
    C[(size_t)(r0 + 1) * N + c0 + 1] = a11;
}

// Whole CC pipeline in one cooperative kernel: M^2, M^4, M^8, M^10, remap.
// Grid must be (N/BT)^2 = 256 blocks (co-resident on 256 CUs).
__global__ __launch_bounds__(256) void k_cc(const float* __restrict__ adj,
                                            float* __restrict__ b0,
                                            float* __restrict__ b1,
                                            float* __restrict__ b2,
                                            float* __restrict__ rmap, int N) {
    cg::grid_group grid = cg::this_grid();
    __shared__ float As[BT][BT + 1];
    __shared__ float Bs[BT][BT + 1];
    mm_tile(adj, adj, b0, N, true,  As, Bs);   // M^2  = (A+I)(A+I)
    grid.sync();
    mm_tile(b0, b0, b1, N, false, As, Bs);     // M^4
    grid.sync();
    mm_tile(b1, b1, b2, N, false, As, Bs);     // M^8
    grid.sync();
    mm_tile(b2, b0, b1, N, false, As, Bs);     // M^10 = M^8 * M^2
    grid.sync();
    // remap[j] = 1 + max({j} U {i != j : M10[i][j] > 1}); symmetric => read row j.
    int wave = blockIdx.x * (blockDim.x >> 6) + (threadIdx.x >> 6);
    int lane = threadIdx.x & 63;
    if (wave < N) {
        const float* row = b1 + (size_t)wave * N;
        int best = wave;
        for (int i = lane; i < N; i += 64)
            if (i != wave && row[i] > 1.0f && i > best) best = i;
        for (int off = 32; off; off >>= 1) {
            int o = __shfl_down(best, off);
            if (o > best) best = o;
        }
        if (lane == 0) rmap[wave] = (float)(best + 1);
    }
}

// Stage 3: gather remap through the winning instance, uint4-vectorized.
__global__ void k_finalize(const unsigned* __restrict__ packed,
                           const float* __restrict__ rmap,
                           float* __restrict__ out, int total, int NB1) {
    int i4 = blockIdx.x * blockDim.x + threadIdx.x;
    if (i4 * 4 >= total) return;
    uint4 v = ((const uint4*)packed)[i4];
    float4 o;
    o.x = v.x ? rmap[NB1 - (int)(v.x & 0x1FFu)] : 0.0f;
    o.y = v.y ? rmap[NB1 - (int)(v.y & 0x1FFu)] : 0.0f;
    o.z = v.z ? rmap[NB1 - (int)(v.z & 0x1FFu)] : 0.0f;
    o.w = v.w ? rmap[NB1 - (int)(v.w & 0x1FFu)] : 0.0f;
    ((float4*)out)[i4] = o;
}

extern "C" void kernel_launch(void* const* d_in, const int* in_sizes, int n_in,
                              void* d_out, int out_size, void* d_ws, size_t ws_size,
                              hipStream_t stream) {
    const float* prob   = (const float*)d_in[0];
    const int*   coords = (const int*)d_in[1];
    const float* adj    = (const float*)d_in[2];
    const int*   dsz1   = (const int*)d_in[4];

    const int NE = in_sizes[0];            // N*h*w = 4718592
    const int NN = in_sizes[2];            // N*N
    int N = (int)(sqrt((double)NN) + 0.5); // 512
    const int HW = NE / N;                 // 9216
    const int total = out_size;            // 1048576
    const int NB1 = N - 1;

    char* ws = (char*)d_ws;
    unsigned* packed = (unsigned*)ws;
    size_t off = (size_t)total * 4;
    float* b0 = (float*)(ws + off); off += (size_t)NN * 4;
    float* b1 = (float*)(ws + off); off += (size_t)NN * 4;
    float* b2 = (float*)(ws + off); off += (size_t)NN * 4;
    float* rmap = (float*)(ws + off);

    hipMemsetAsync(packed, 0, (size_t)total * 4, stream);

    k_scatter<<<(NE / 4 + 255) / 256, 256, 0, stream>>>(prob, coords, packed,
                                                        NE, HW, NB1, dsz1);

    int nblk = (N / BT) * (N / BT);  // 256
    void* args[] = {(void*)&adj, (void*)&b0, (void*)&b1, (void*)&b2,
                    (void*)&rmap, (void*)&N};
    hipLaunchCooperativeKernel((const void*)k_cc, dim3(nblk), dim3(256),
                               args, 0, stream);

    k_finalize<<<(total / 4 + 255) / 256, 256, 0, stream>>>(packed, rmap,
                                                            (float*)d_out,
                                                            total, NB1);
}

// Round 4
// 155.266 us; speedup vs baseline: 1.9625x; 1.9625x over previous
//
#include <hip/hip_runtime.h>
#include <math.h>

#define MASK_THR 0.53f
#define BT 32

// ---- matmul tile: one 32x32 output tile per block, 2x2 register blocking ----
// addI: treat both inputs as (X + I) while loading (for M^2 = (A+I)^2).
__device__ __forceinline__ void mm_tile(const float* __restrict__ A,
                                        const float* __restrict__ B,
                                        float* __restrict__ C, int N, bool addI,
                                        int bid) {
    __shared__ float As[BT][BT + 1];
    __shared__ float Bs[BT][BT + 1];
    int tid = threadIdx.x;
    int NT = N / BT;
    int bx = bid % NT, by = bid / NT;
    int rowBase = by * BT, colBase = bx * BT;
    int tx = tid & 15, ty = tid >> 4;
    int lr = tid >> 3;
    int lc = (tid & 7) * 4;
    float a00 = 0, a01 = 0, a10 = 0, a11 = 0;
    for (int t = 0; t < N; t += BT) {
        float4 av = *(const float4*)&A[(size_t)(rowBase + lr) * N + t + lc];
        float4 bv = *(const float4*)&B[(size_t)(t + lr) * N + colBase + lc];
        if (addI) {
            int r = rowBase + lr, c = t + lc;
            if (r == c + 0) av.x += 1.0f;
            if (r == c + 1) av.y += 1.0f;
            if (r == c + 2) av.z += 1.0f;
            if (r == c + 3) av.w += 1.0f;
            int r2 = t + lr, c2 = colBase + lc;
            if (r2 == c2 + 0) bv.x += 1.0f;
            if (r2 == c2 + 1) bv.y += 1.0f;
            if (r2 == c2 + 2) bv.z += 1.0f;
            if (r2 == c2 + 3) bv.w += 1.0f;
        }
        As[lr][lc + 0] = av.x; As[lr][lc + 1] = av.y;
        As[lr][lc + 2] = av.z; As[lr][lc + 3] = av.w;
        Bs[lr][lc + 0] = bv.x; Bs[lr][lc + 1] = bv.y;
        Bs[lr][lc + 2] = bv.z; Bs[lr][lc + 3] = bv.w;
        __syncthreads();
#pragma unroll
        for (int k = 0; k < BT; ++k) {
            float a0 = As[ty * 2][k], a1 = As[ty * 2 + 1][k];
            float b0 = Bs[k][tx * 2], b1 = Bs[k][tx * 2 + 1];
            a00 += a0 * b0; a01 += a0 * b1;
            a10 += a1 * b0; a11 += a1 * b1;
        }
        __syncthreads();
    }
    int r0 = rowBase + ty * 2, c0 = colBase + tx * 2;
    C[(size_t)r0 * N + c0] = a00;
    C[(size_t)r0 * N + c0 + 1] = a01;
    C[(size_t)(r0 + 1) * N + c0] = a10;
    C[(size_t)(r0 + 1) * N + c0 + 1] = a11;
}

// ---- hybrid stage: blocks [0,nMM) do one matmul stage; the rest scatter a
// chunk of the pixels. The two are data-independent; stage ordering carries
// the matmul dependency chain. ----
// Scatter packing: p in [0.53,1) => exponent fixed 126, mantissa orders as p.
// Output needs only winner's instance n, so pack (mant<<9)|(NB1-n):
// atomicMax = max prob, tie -> min n. Stale-read filter is monotone-safe
// (packed only increases; stale "already >= v" can never wrongly skip).
__global__ __launch_bounds__(256) void k_stage(const float* __restrict__ A,
                                               const float* __restrict__ B,
                                               float* __restrict__ C, int N,
                                               int addI,
                                               const float* __restrict__ prob,
                                               const int* __restrict__ coords,
                                               unsigned* __restrict__ packed,
                                               int NE, int HW, int NB1,
                                               const int* __restrict__ d_size1,
                                               int chunkBase, int chunkEnd,
                                               int nMM) {
    if ((int)blockIdx.x < nMM) {
        mm_tile(A, B, C, N, addI != 0, blockIdx.x);
        return;
    }
    int i4 = chunkBase + (blockIdx.x - nMM) * blockDim.x + threadIdx.x;
    if (i4 >= chunkEnd) return;
    int size1 = *d_size1;
    float4 p = ((const float4*)prob)[i4];
    int4 x = ((const int4*)coords)[i4];
    int4 y = ((const int4*)(coords + NE))[i4];
    int base = i4 * 4;
    float pv[4] = {p.x, p.y, p.z, p.w};
    int   xv[4] = {x.x, x.y, x.z, x.w};
    int   yv[4] = {y.x, y.y, y.z, y.w};
#pragma unroll
    for (int e = 0; e < 4; ++e) {
        if (pv[e] >= MASK_THR) {
            unsigned n = (unsigned)(base + e) / (unsigned)HW;
            unsigned v = ((__float_as_uint(pv[e]) & 0x7FFFFFu) << 9) |
                         (unsigned)(NB1 - (int)n);
            unsigned* addr = &packed[xv[e] * size1 + yv[e]];
            if (*addr < v) atomicMax(addr, v);
        }
    }
}

// remap[j] = 1 + max({j} U {i != j : M10[i][j] > 1}); classification is
// symmetric (symmetric adjacency; >1 test exact under fp32) => read ROW j.
__global__ void k_remap(const float* __restrict__ P10, float* __restrict__ rmap,
                        int N) {
    int j = blockIdx.x;
    int lane = threadIdx.x;  // 64
    const float* row = P10 + (size_t)j * N;
    int best = j;
    for (int i = lane; i < N; i += 64)
        if (i != j && row[i] > 1.0f && i > best) best = i;
    for (int off = 32; off; off >>= 1) {
        int o = __shfl_down(best, off);
        if (o > best) best = o;
    }
    if (lane == 0) rmap[j] = (float)(best + 1);
}

__global__ void k_finalize(const unsigned* __restrict__ packed,
                           const float* __restrict__ rmap,
                           float* __restrict__ out, int total, int NB1) {
    int i4 = blockIdx.x * blockDim.x + threadIdx.x;
    if (i4 * 4 >= total) return;
    uint4 v = ((const uint4*)packed)[i4];
    float4 o;
    o.x = v.x ? rmap[NB1 - (int)(v.x & 0x1FFu)] : 0.0f;
    o.y = v.y ? rmap[NB1 - (int)(v.y & 0x1FFu)] : 0.0f;
    o.z = v.z ? rmap[NB1 - (int)(v.z & 0x1FFu)] : 0.0f;
    o.w = v.w ? rmap[NB1 - (int)(v.w & 0x1FFu)] : 0.0f;
    ((float4*)out)[i4] = o;
}

extern "C" void kernel_launch(void* const* d_in, const int* in_sizes, int n_in,
                              void* d_out, int out_size, void* d_ws, size_t ws_size,
                              hipStream_t stream) {
    const float* prob   = (const float*)d_in[0];
    const int*   coords = (const int*)d_in[1];
    const float* adj    = (const float*)d_in[2];
    const int*   dsz1   = (const int*)d_in[4];

    const int NE = in_sizes[0];            // N*h*w = 4718592
    const int NN = in_sizes[2];            // N*N
    int N = (int)(sqrt((double)NN) + 0.5); // 512
    const int HW = NE / N;                 // 9216
    const int total = out_size;            // 1048576
    const int NB1 = N - 1;

    char* ws = (char*)d_ws;
    unsigned* packed = (unsigned*)ws;
    size_t off = (size_t)total * 4;
    float* b0 = (float*)(ws + off); off += (size_t)NN * 4;
    float* b1 = (float*)(ws + off); off += (size_t)NN * 4;
    float* b2 = (float*)(ws + off); off += (size_t)NN * 4;
    float* rmap = (float*)(ws + off);

    hipMemsetAsync(packed, 0, (size_t)total * 4, stream);

    const int nMM = (N / BT) * (N / BT);       // 256 matmul blocks
    const int i4total = NE / 4;                // 1179648
    const int chunk = (i4total + 3) / 4;       // pixels-vec4 per stage
    const int sBlocks = (chunk + 255) / 256;   // scatter blocks per stage
    dim3 grid(nMM + sBlocks);

    for (int s = 0; s < 4; ++s) {
        const float *Ap, *Bp; float* Cp; int addI = 0;
        switch (s) {
            case 0: Ap = adj; Bp = adj; Cp = b0; addI = 1; break; // M^2
            case 1: Ap = b0;  Bp = b0;  Cp = b1; break;           // M^4
            case 2: Ap = b1;  Bp = b1;  Cp = b2; break;           // M^8
            default: Ap = b2; Bp = b0;  Cp = b1; break;           // M^10
        }
        int cb = s * chunk;
        int ce = min(cb + chunk, i4total);
        k_stage<<<grid, 256, 0, stream>>>(Ap, Bp, Cp, N, addI,
                                          prob, coords, packed,
                                          NE, HW, NB1, dsz1, cb, ce, nMM);
    }

    k_remap<<<N, 64, 0, stream>>>(b1, rmap, N);

    k_finalize<<<(total / 4 + 255) / 256, 256, 0, stream>>>(packed, rmap,
                                                            (float*)d_out,
                                                            total, NB1);
}